// Round 4
// baseline (297.197 us; speedup 1.0000x reference)
//
#include <hip/hip_runtime.h>

// WaveConv1d on MI355X — round 15: einsum_v9 (contiguous w reads, H1 test).
//   out = x + idwt(E1(lo4)-lo4, E2(h4)-h4, 0, 0, 0)
// r14 post-mortem: v5/v6/v8 (3 different schedules) all ~113-130us; all pipes
// <50%; FETCH 227MB / 113us = 2.0 TB/s exactly. Theory H1: HBM-bound at ~2TB/s
// effective because w requests are 256B (64-lane dword) at 2088B stride across
// ~1500 blocks -> DRAM page locality destroyed. v9 re-tiles k into thirds
// (192/192/138): each wave reads its w row as ONE dwordx4 spanning 784B
// contiguous (rows 8B-aligned -> start 2 floats early for odd (o+j); shift is
// compile-time per j since o=4*oq). w: reg -> LDS, 2-chunk lookahead, lgkm-only
// raw barriers (reg loads survive). x: L2-resident (stride-24 grid mapping pins
// oq-siblings to one XCD since 24%8==0), reg-prefetched dwordx2, no LDS.

#define NROWS 4096          // B*C
#define MODES 522

#define M1 4101
#define M2 2056
#define M3 1033
#define M4 522

typedef unsigned int  uint;
typedef unsigned short ushort;

__constant__ float c_dlo[12] = {
  -0.00107730108499558f,  0.004777257511010651f,  0.0005538422009938016f,
  -0.031582039318031156f, 0.02752286553001629f,   0.09750160558707936f,
  -0.12976686756709563f,  -0.22626469396516913f,  0.3152503517092432f,
   0.7511339080215775f,   0.4946238903983854f,    0.11154074335008017f };
__constant__ float c_dhi[12] = {
  -0.11154074335008017f,  0.4946238903983854f,   -0.7511339080215775f,
   0.3152503517092432f,   0.22626469396516913f,  -0.12976686756709563f,
  -0.09750160558707936f,  0.02752286553001629f,   0.031582039318031156f,
   0.0005538422009938016f,-0.004777257511010651f, -0.00107730108499558f };
// Analysis (time-reversed) filters
__constant__ float c_alo[12] = {
   0.11154074335008017f,  0.4946238903983854f,    0.7511339080215775f,
   0.3152503517092432f,  -0.22626469396516913f,  -0.12976686756709563f,
   0.09750160558707936f,  0.02752286553001629f,  -0.031582039318031156f,
   0.0005538422009938016f, 0.004777257511010651f, -0.00107730108499558f };
__constant__ float c_ahi[12] = {
  -0.00107730108499558f, -0.004777257511010651f,  0.0005538422009938016f,
   0.031582039318031156f, 0.02752286553001629f,  -0.09750160558707936f,
  -0.12976686756709563f,  0.22626469396516913f,   0.3152503517092432f,
  -0.7511339080215775f,   0.4946238903983854f,   -0.11154074335008017f };

__device__ __forceinline__ ushort f2bf(float f) {
    uint b = __float_as_uint(f);
    uint r = (b + 0x7fffu + ((b >> 16) & 1u)) >> 16;
    return (ushort)r;
}

// One lo-only analysis level LDS->LDS, interior fast path (no reflect).
__device__ __forceinline__
void dwt_lo_lds(const float* __restrict__ src, int n, int m,
                float* __restrict__ dst, int tid)
{
    int jhi = (n - 2) >> 1;
    for (int j = tid; j < m; j += 256) {
        float a = 0.f;
        if (j >= 5 && j <= jhi) {
            const float* s = src + 2 * j - 10;
#pragma unroll
            for (int t = 0; t < 12; ++t) a += s[t] * c_alo[t];
        } else {
            int base = 2 * j - 10;
#pragma unroll
            for (int t = 0; t < 12; ++t) {
                int u = base + t;
                u = (u < 0) ? (-1 - u) : u;
                u = (u >= n) ? (2 * n - 1 - u) : u;
                a += src[u] * c_alo[t];
            }
        }
        dst[j] = a;
    }
}

// Fused forward DWT, lo-chain only: x -> (lo4, h4). One block per row.
__global__ __launch_bounds__(256)
void dwt_fused2(const float* __restrict__ x,
                float* __restrict__ lo4g, float* __restrict__ h4g)
{
    __shared__ float X[8192];
    __shared__ float LA[4104];
    int row = blockIdx.x, tid = threadIdx.x;

    const float4* xr = (const float4*)(x + (size_t)row * 8192);
    float4* Xv = (float4*)X;
#pragma unroll
    for (int i = 0; i < 8; ++i) Xv[tid + 256 * i] = xr[tid + 256 * i];
    __syncthreads();

    dwt_lo_lds(X,  8192, M1, LA, tid);
    __syncthreads();
    dwt_lo_lds(LA, M1,   M2, X,  tid);
    __syncthreads();
    dwt_lo_lds(X,  M2,   M3, LA, tid);
    __syncthreads();

    float* lo4r = lo4g + (size_t)row * M4;
    float* h4r  = h4g  + (size_t)row * M4;
    int jhi = (M3 - 2) >> 1;
    for (int j = tid; j < M4; j += 256) {
        float alo = 0.f, ahi = 0.f;
        if (j >= 5 && j <= jhi) {
            const float* s = LA + 2 * j - 10;
#pragma unroll
            for (int t = 0; t < 12; ++t) {
                float v = s[t];
                alo += v * c_alo[t]; ahi += v * c_ahi[t];
            }
        } else {
            int base = 2 * j - 10;
#pragma unroll
            for (int t = 0; t < 12; ++t) {
                int u = base + t;
                u = (u < 0) ? (-1 - u) : u;
                u = (u >= M3) ? (2 * M3 - 1 - u) : u;
                float v = LA[u];
                alo += v * c_alo[t]; ahi += v * c_ahi[t];
            }
        }
        lo4r[j] = alo; h4r[j] = ahi;
    }
}

// xpose2: [b][c][k] fp32 -> bf16 xT [c][g=4][k=522][b4] (g = b>>2, b4 = b&3).
// One block per (c, tensor). ALSO zero-fills dlo/dh (2*SZ contiguous floats)
// for einsum_v9's atomicAdd accumulation (stream order guarantees completion
// before einsum launches).
__global__ __launch_bounds__(256)
void xpose2(const float* __restrict__ lo4, const float* __restrict__ h4,
            ushort* __restrict__ xlT, ushort* __restrict__ xhT,
            float* __restrict__ dzero)
{
    __shared__ float L[16][528];
    int c = blockIdx.x;
    const float* src = blockIdx.y ? h4 : lo4;
    ushort*      dst = blockIdx.y ? xhT : xlT;
    int t = threadIdx.x;

    // zero dlo+dh: 2*SZ floats over 512 blocks x 256 thr
    {
        const size_t nz = ((size_t)2 * NROWS * M4) / 4;
        size_t gid = ((size_t)blockIdx.y * gridDim.x + blockIdx.x) * 256 + t;
        float4 z4 = make_float4(0.f, 0.f, 0.f, 0.f);
        float4* zp = (float4*)dzero;
        for (size_t i = gid; i < nz; i += (size_t)512 * 256) zp[i] = z4;
    }

#pragma unroll
    for (int b = 0; b < 16; ++b)
        for (int k = t; k < MODES; k += 256)
            L[b][k] = src[((size_t)b * 256 + c) * MODES + k];
    __syncthreads();

#pragma unroll
    for (int g = 0; g < 4; ++g) {
        for (int k = t; k < MODES; k += 256) {
            ushort4 v;
            v.x = f2bf(L[4*g+0][k]);
            v.y = f2bf(L[4*g+1][k]);
            v.z = f2bf(L[4*g+2][k]);
            v.w = f2bf(L[4*g+3][k]);
            *(ushort4*)&dst[(((size_t)c * 4 + g) * MODES + k) * 4] = v;
        }
    }
}

// Delta-IDWT: A = dlo-lo4, Hs = dh-h4; lvl4 full -> lvl3,2,1 lo-only -> +x.
__global__ __launch_bounds__(256)
void idwt_delta2(const float* __restrict__ dlo, const float* __restrict__ dh,
                 const float* __restrict__ lo4, const float* __restrict__ h4,
                 const float* __restrict__ x,   float* __restrict__ out)
{
    __shared__ float A[2056];
    __shared__ float B[4104];
    __shared__ float Hs[528];
    int row = blockIdx.x, tid = threadIdx.x;

    for (int i = tid; i < M4; i += 256) {
        size_t idx = (size_t)row * M4 + i;
        A[i]  = dlo[idx] - lo4[idx];
        Hs[i] = dh[idx]  - h4[idx];
    }
    __syncthreads();

    for (int jj = tid; jj < M4 - 5; jj += 256) {
        float e = 0.f, od = 0.f;
#pragma unroll
        for (int s = 0; s < 6; ++s) {
            float xv = A[jj + s], hv = Hs[jj + s];
            e  += xv * c_dlo[2*s+1] + hv * c_dhi[2*s+1];
            od += xv * c_dlo[2*s]   + hv * c_dhi[2*s];
        }
        B[2*jj] = e; B[2*jj+1] = od;
    }
    __syncthreads();

    for (int jj = tid; jj < M3 - 5; jj += 256) {
        float e = 0.f, od = 0.f;
#pragma unroll
        for (int s = 0; s < 6; ++s) {
            float xv = B[jj + s];
            e  += xv * c_dlo[2*s+1];
            od += xv * c_dlo[2*s];
        }
        A[2*jj] = e; A[2*jj+1] = od;
    }
    __syncthreads();

    for (int jj = tid; jj < M2 - 5; jj += 256) {
        float e = 0.f, od = 0.f;
#pragma unroll
        for (int s = 0; s < 6; ++s) {
            float xv = A[jj + s];
            e  += xv * c_dlo[2*s+1];
            od += xv * c_dlo[2*s];
        }
        B[2*jj] = e; B[2*jj+1] = od;
    }
    __syncthreads();

    const float2* x2 = (const float2*)(x + (size_t)row * 8192);
    float2* o2 = (float2*)(out + (size_t)row * 8192);
    for (int jj = tid; jj < M1 - 5; jj += 256) {
        float e = 0.f, od = 0.f;
#pragma unroll
        for (int s = 0; s < 6; ++s) {
            float xv = B[jj + s];
            e  += xv * c_dlo[2*s+1];
            od += xv * c_dlo[2*s];
        }
        float2 xv2 = x2[jj];
        o2[jj] = make_float2(xv2.x + e, xv2.y + od);
    }
}

// Dual einsum v9: contiguous w reads (784B dwordx4 per row), k-thirds.
// dlo[b,o,k] += sum_{i in quarter} x[b,i,k]*w[i,o,k]  (atomics; zeroed in xpose2)
// Grid 1536 = 64 oq x 24 c, wg = oq*24 + c, c = (e*3+r)*4+ih.
//   (24 % 8 == 0 -> all 64 oq-siblings of a (e,r,ih) x-slice land on one XCD.)
// Block: 4 waves (wave wv owns b-quad g=wv), o = 4*oq, k-range r: KO=r*192,
// width 192/192/138, i-range [ih*64, ih*64+64), 64 chunks of 1 i.
// w: wave wv reads row (i,o+wv) floats [KO, KO+KW) as ONE dwordx4 load of
// NL lanes (49/35) starting 2 floats early when (o+wv) odd (rows 8B-aligned;
// shift sj=2*(wv&1) is compile-time per j). reg double-buffer (wA/wB), 2-chunk
// lookahead, ds_write 1 chunk ahead, raw "lgkmcnt(0); s_barrier" (no vmcnt
// drain -> w/x reg loads stay in flight across barriers; compiler inserts
// counted vmcnt before the dependent ds_write/use).
// x: L2-resident (XCD-pinned slice ~786KB), reg-prefetched dwordx2 per pass.
// acc[3][4][4]; flush via atomicAdd with kk<522 mask (covers r2 p2 tail).
__global__ __launch_bounds__(256)
void einsum_v9(const ushort* __restrict__ xlT, const ushort* __restrict__ xhT,
               const float* __restrict__ w1,   const float* __restrict__ w2,
               float* __restrict__ dlo, float* __restrict__ dh)
{
    __shared__ float W[2][4][200];   // [buf][j][sj + 192 + pad]; 6.4 KB

    int wg = blockIdx.x;
    int oq = wg / 24;
    int c  = wg - oq * 24;
    int ih = c & 3;
    int er = c >> 2;            // 0..5
    int e  = (er >= 3);
    int r  = er - 3 * e;

    const ushort* xT = e ? xhT : xlT;
    const float*  w  = e ? w2  : w1;
    float* outp      = e ? dh  : dlo;

    const int KO = r * 192;
    const int NL = (r == 2) ? 35 : 49;    // float4 lanes per w row
    int lane = threadIdx.x & 63;
    int wv   = threadIdx.x >> 6;
    int o    = oq * 4;
    int i0   = ih * 64;

    // ---- w row base (wave wv stages row j=wv of each i) ----
    const int sj = 2 * (wv & 1);          // 16B-align shift (o even)
    const float* wrow = w + ((size_t)i0 * 256 + o + wv) * MODES + KO - sj;
    const size_t WI = (size_t)256 * MODES;    // floats per i

    // ---- x per-pass bases (dwordx2, L2-hit), clamped tail for r2 p2 ----
    int k2 = KO + 128 + lane; if (k2 > 521) k2 = 521;
    const size_t xrow = (size_t)(i0 * 4 + wv) * MODES;
    const ushort* xb0 = xT + (xrow + (size_t)(KO + lane)) * 4;
    const ushort* xb1 = xT + (xrow + (size_t)(KO + 64 + lane)) * 4;
    const ushort* xb2 = xT + (xrow + (size_t)k2) * 4;
    const size_t XI = (size_t)4 * MODES * 4;  // ushorts per i

    float acc[3][4][4];
#pragma unroll
    for (int p = 0; p < 3; ++p)
#pragma unroll
        for (int q = 0; q < 4; ++q)
#pragma unroll
            for (int j = 0; j < 4; ++j) acc[p][q][j] = 0.f;

#define PASS(BUF, P, XP) do {                                                 \
    float f0 = W[BUF][0][(P) * 64 + lane];                                    \
    float f1 = W[BUF][1][2 + (P) * 64 + lane];                                \
    float f2 = W[BUF][2][(P) * 64 + lane];                                    \
    float f3 = W[BUF][3][2 + (P) * 64 + lane];                                \
    float x0 = __uint_as_float((XP).x << 16);                                 \
    float x1 = __uint_as_float((XP).x & 0xffff0000u);                         \
    float x2 = __uint_as_float((XP).y << 16);                                 \
    float x3 = __uint_as_float((XP).y & 0xffff0000u);                         \
    acc[P][0][0] += x0*f0; acc[P][0][1] += x0*f1;                             \
    acc[P][0][2] += x0*f2; acc[P][0][3] += x0*f3;                             \
    acc[P][1][0] += x1*f0; acc[P][1][1] += x1*f1;                             \
    acc[P][1][2] += x1*f2; acc[P][1][3] += x1*f3;                             \
    acc[P][2][0] += x2*f0; acc[P][2][1] += x2*f1;                             \
    acc[P][2][2] += x2*f2; acc[P][2][3] += x2*f3;                             \
    acc[P][3][0] += x3*f0; acc[P][3][1] += x3*f1;                             \
    acc[P][3][2] += x3*f2; acc[P][3][3] += x3*f3;                             \
} while (0)

#define RAWBAR asm volatile("s_waitcnt lgkmcnt(0)\n\ts_barrier" ::: "memory")

    float4 wA = make_float4(0.f,0.f,0.f,0.f), wB = wA;
    uint2 a0, a1, a2, b0, b1, b2;

    // ---- prologue: w(i0)->LDS[0]; w(i0+1)->wB; x(i0)->a* ----
    if (lane < NL) {
        wA = *(const float4*)(wrow + 4 * lane);
        *(float4*)&W[0][wv][4 * lane] = wA;
        wB = *(const float4*)(wrow + WI + 4 * lane);
    }
    a0 = *(const uint2*)(xb0);
    a1 = *(const uint2*)(xb1);
    a2 = *(const uint2*)(xb2);
    RAWBAR;

    for (int ch = 0; ch < 64; ch += 2) {
        // ---- even: compute ch from W[0]/a*; stage ch+1 write, ch+2 load ----
        if (lane < NL) {
            if (ch + 2 < 64)
                wA = *(const float4*)(wrow + (size_t)(ch + 2) * WI + 4 * lane);
            *(float4*)&W[1][wv][4 * lane] = wB;     // chunk ch+1
        }
        b0 = *(const uint2*)(xb0 + (size_t)(ch + 1) * XI);
        b1 = *(const uint2*)(xb1 + (size_t)(ch + 1) * XI);
        b2 = *(const uint2*)(xb2 + (size_t)(ch + 1) * XI);
        PASS(0, 0, a0); PASS(0, 1, a1); PASS(0, 2, a2);
        RAWBAR;

        // ---- odd: compute ch+1 from W[1]/b*; stage ch+2 write, ch+3 load ----
        if (lane < NL) {
            if (ch + 3 < 64)
                wB = *(const float4*)(wrow + (size_t)(ch + 3) * WI + 4 * lane);
            if (ch + 2 < 64)
                *(float4*)&W[0][wv][4 * lane] = wA; // chunk ch+2
        }
        if (ch + 2 < 64) {
            a0 = *(const uint2*)(xb0 + (size_t)(ch + 2) * XI);
            a1 = *(const uint2*)(xb1 + (size_t)(ch + 2) * XI);
            a2 = *(const uint2*)(xb2 + (size_t)(ch + 2) * XI);
        }
        PASS(1, 0, b0); PASS(1, 1, b1); PASS(1, 2, b2);
        RAWBAR;
    }
#undef PASS
#undef RAWBAR

    // ---- flush: atomic accumulate (4 ih-parts per element) ----
#pragma unroll
    for (int p = 0; p < 3; ++p) {
        int kk = KO + p * 64 + lane;
        if (kk < MODES) {
#pragma unroll
            for (int q = 0; q < 4; ++q) {
                int b = 4 * wv + q;
#pragma unroll
                for (int j = 0; j < 4; ++j)
                    atomicAdd(&outp[((size_t)b * 256 + o + j) * MODES + kk],
                              acc[p][q][j]);
            }
        }
    }
}

extern "C" void kernel_launch(void* const* d_in, const int* in_sizes, int n_in,
                              void* d_out, int out_size, void* d_ws, size_t ws_size,
                              hipStream_t stream)
{
    const float* x  = (const float*)d_in[0];
    const float* w1 = (const float*)d_in[1];
    const float* w2 = (const float*)d_in[2];
    float* out = (float*)d_out;
    float* ws  = (float*)d_ws;

    const size_t SZ = (size_t)NROWS * M4;   // 2,138,112
    float* lo4 = ws;
    float* h4  = lo4 + SZ;
    float* dlo = h4  + SZ;
    float* dh  = dlo + SZ;                   // dlo,dh contiguous (zeroed together)
    ushort* xlT = (ushort*)(dh + SZ);        // SZ ushorts
    ushort* xhT = xlT + SZ;                  // SZ ushorts

    dim3 blk(256);

    dwt_fused2<<<NROWS, blk, 0, stream>>>(x, lo4, h4);
    xpose2<<<dim3(256, 2), blk, 0, stream>>>(lo4, h4, xlT, xhT, dlo);
    einsum_v9<<<1536, blk, 0, stream>>>(xlT, xhT, w1, w2, dlo, dh);
    idwt_delta2<<<NROWS, blk, 0, stream>>>(dlo, dh, lo4, h4, x, out);
}